// Round 2
// baseline (2361.061 us; speedup 1.0000x reference)
//
#include <hip/hip_runtime.h>
#include <cstdint>
#include <cstddef>

// ---------------------------------------------------------------------------
// EdgeDecoder, transposed formulation:
//   H0^T = W0^T · X^T   (weights = A operand from LDS, gathered edges = B)
//   H1^T = W1^T · H0^T  (W1^T frags streamed from prepacked global/L2)
//   p    = (W2 replicated-rows) · H1^T  (final MFMA, all D rows equal p)
// Inter-layer C->B layout transform is a pure register re-pack (zero LDS,
// zero shuffles) because W1^T / W2 are prepacked with the matching
// k-permutation: frag[kk2] elem i of lane (n,g) := acc[2*kk2+(i>>2)][i&3].
// LDS = 68.5 KB -> 2 blocks/CU; __launch_bounds__(512,4) caps VGPR at 128.
// ---------------------------------------------------------------------------

#define E_EDGES   1000000
#define NTILES    31250          // E / 32
#define NUSER_H   12800000       // 100000*128 halfs
#define NITEM_H   6400000        // 50000*128
#define WB        19200000       // half index where prepacked weights start
#define DSTRIDE   51456          // per-decoder prepacked halfs
#define W1_OFF    32768          // within decoder region
#define B0_OFF    49152
#define B1_OFF    49280
#define W2_OFF    49408
// LDS (halfs): w0t 0..32767 | b0 32768..32895 | b1 32896..33023 | w2f 33024..35071
#define LDS_H     35072

typedef _Float16 half8  __attribute__((ext_vector_type(8)));
typedef _Float16 half4v __attribute__((ext_vector_type(4)));
typedef float    f32x4  __attribute__((ext_vector_type(4)));

__device__ __forceinline__ float elu(float x) {
    return x > 0.f ? x : (__expf(x) - 1.f);
}

// ---- prep: fp32 embeddings -> f16 tables ----------------------------------
__global__ void prep_emb(const float* __restrict__ user_emb,
                         const float* __restrict__ item_emb,
                         _Float16* __restrict__ ws) {
    int i = blockIdx.x * 256 + threadIdx.x;        // float4 index over 4.8M
    const float* src; _Float16* dst;
    if (i < 3200000) { src = user_emb; dst = ws; }
    else { i -= 3200000; src = item_emb; dst = ws + NUSER_H; }
    float4 f = ((const float4*)src)[i];
    half4v h;
    h[0] = (_Float16)f.x; h[1] = (_Float16)f.y;
    h[2] = (_Float16)f.z; h[3] = (_Float16)f.w;
    ((half4v*)dst)[i] = h;
}

// ---- prep: weights -> prepacked f16 fragment order ------------------------
__global__ void prep_w(const float* __restrict__ W0_ui, const float* __restrict__ W1_ui,
                       const float* __restrict__ W2_ui, const float* __restrict__ b0_ui,
                       const float* __restrict__ b1_ui,
                       const float* __restrict__ W0_iu, const float* __restrict__ W1_iu,
                       const float* __restrict__ W2_iu, const float* __restrict__ b0_iu,
                       const float* __restrict__ b1_iu,
                       _Float16* __restrict__ wdst) {
    const int wid = blockIdx.x * 4 + (threadIdx.x >> 6);
    const int l = threadIdx.x & 63;
    const int n = l & 15, g = l >> 4;
    if (wid < 128) {
        // W0^T A-frags: frag f=kk*8+j; lane: row c1 = j*16+n, k = kk*32+g*8+i
        const int dec = wid >> 6, f = wid & 63;
        const float* W0 = dec ? W0_iu : W0_ui;
        const int kk = f >> 3, j = f & 7;
        half8 fr;
        #pragma unroll
        for (int i = 0; i < 8; ++i)
            fr[i] = (_Float16)W0[(kk * 32 + g * 8 + i) * 128 + j * 16 + n];
        *(half8*)&wdst[dec * DSTRIDE + f * 512 + l * 8] = fr;
    } else if (wid < 192) {
        // W1^T A-frags with permuted k-order matching the register re-pack:
        // k-pos (kk2, quad g, i) <-> channel c1 = (2*kk2+(i>>2))*16 + g*4 + (i&3)
        const int q = wid - 128, dec = q >> 5, f = q & 31;
        const float* W1 = dec ? W1_iu : W1_ui;
        const int kk2 = f >> 3, j2 = f & 7;
        half8 fr;
        #pragma unroll
        for (int i = 0; i < 8; ++i) {
            const int c1 = (2 * kk2 + (i >> 2)) * 16 + g * 4 + (i & 3);
            fr[i] = (_Float16)W1[c1 * 128 + j2 * 16 + n];
        }
        *(half8*)&wdst[dec * DSTRIDE + W1_OFF + f * 512 + l * 8] = fr;
    } else if (wid < 200) {
        // W2 replicated-row A-frags, same permuted k-order over c2
        const int q = wid - 192, dec = q >> 2, kkf = q & 3;
        const float* W2 = dec ? W2_iu : W2_ui;
        half8 fr;
        #pragma unroll
        for (int i = 0; i < 8; ++i)
            fr[i] = (_Float16)W2[(2 * kkf + (i >> 2)) * 16 + g * 4 + (i & 3)];
        *(half8*)&wdst[dec * DSTRIDE + W2_OFF + kkf * 512 + l * 8] = fr;
    } else if (wid < 202) {
        const int dec = wid - 200;
        const float* b0 = dec ? b0_iu : b0_ui;
        const float* b1 = dec ? b1_iu : b1_ui;
        _Float16* d = wdst + dec * DSTRIDE;
        d[B0_OFF + 2 * l]     = (_Float16)b0[2 * l];
        d[B0_OFF + 2 * l + 1] = (_Float16)b0[2 * l + 1];
        d[B1_OFF + 2 * l]     = (_Float16)b1[2 * l];
        d[B1_OFF + 2 * l + 1] = (_Float16)b1[2 * l + 1];
    }
}

// ---- main ------------------------------------------------------------------
template<bool PRE16>
__global__ __launch_bounds__(512, 4) void edge_mlp(
    const _Float16* __restrict__ tab16,     // f16 tables base (user @0, item @NUSER_H)
    const _Float16* __restrict__ wpre,      // prepacked weights base
    const float* __restrict__ user_f32, const float* __restrict__ item_f32,
    const int* __restrict__ ui_src, const int* __restrict__ ui_dst,
    const int* __restrict__ iu_src, const int* __restrict__ iu_dst,
    const float* __restrict__ b2_ui, const float* __restrict__ b2_iu,
    float* __restrict__ out)
{
    __shared__ __align__(16) _Float16 lds[LDS_H];
    const int tid = threadIdx.x;
    const int l = tid & 63, w = tid >> 6;
    const int n = l & 15, g = l >> 4;
    const int dec = (int)(blockIdx.x >> 9);
    const int b9  = (int)(blockIdx.x & 511);

    const _Float16* stab16 = dec ? tab16 + NUSER_H : tab16;
    const _Float16* dtab16 = dec ? tab16 : tab16 + NUSER_H;
    const float* stab32 = dec ? item_f32 : user_f32;
    const float* dtab32 = dec ? user_f32 : item_f32;
    const int* sidx = dec ? iu_src : ui_src;
    const int* didx = dec ? iu_dst : ui_dst;
    const _Float16* wreg = wpre + (size_t)dec * DSTRIDE;
    const float b2s = dec ? b2_iu[0] : b2_ui[0];
    float* op = out + dec * E_EDGES;

    // stage W0^T frags (64 KB) + biases + W2 frags (2304 halfs) into LDS
    #pragma unroll
    for (int q = 0; q < 8; ++q) {
        const int f = w * 8 + q;
        *(half8*)&lds[f * 512 + l * 8] = *(const half8*)&wreg[f * 512 + l * 8];
    }
    if (tid < 288)
        *(half8*)&lds[32768 + tid * 8] = *(const half8*)&wreg[B0_OFF + tid * 8];
    __syncthreads();

    const half8* w0f = (const half8*)lds;               // frag f: [f*64 + l]
    const _Float16* b0l = &lds[32768];
    const _Float16* b1l = &lds[32896];
    const half8* w2f = (const half8*)&lds[33024];       // frag kkf: [kkf*64 + l]
    const half8* w1f = (const half8*)&wreg[W1_OFF];     // global frags [f*64 + l]

    for (int t = b9 * 8 + w; t < NTILES; t += 4096) {
        const int e0 = t * 32;

        // ---- gather B-frags (edges): lane holds edge = n, k-chunk by quad ----
        half8 a0[2][8];
        #pragma unroll
        for (int s = 0; s < 2; ++s) {
            const int e = e0 + s * 16 + n;
            const int si = sidx[e];
            const int di = didx[e];
            if (PRE16) {
                const _Float16* rs = stab16 + ((unsigned)si << 7);
                const _Float16* rd = dtab16 + ((unsigned)di << 7);
                #pragma unroll
                for (int kk = 0; kk < 4; ++kk) a0[s][kk]     = *(const half8*)(rs + kk * 32 + g * 8);
                #pragma unroll
                for (int kk = 0; kk < 4; ++kk) a0[s][4 + kk] = *(const half8*)(rd + kk * 32 + g * 8);
            } else {
                const float* rs = stab32 + (size_t)si * 128;
                const float* rd = dtab32 + (size_t)di * 128;
                #pragma unroll
                for (int kk = 0; kk < 8; ++kk) {
                    const float* base = (kk < 4) ? (rs + kk * 32 + g * 8)
                                                 : (rd + (kk - 4) * 32 + g * 8);
                    float4 p0 = *(const float4*)base;
                    float4 p1 = *(const float4*)(base + 4);
                    half8 fr;
                    fr[0] = (_Float16)p0.x; fr[1] = (_Float16)p0.y;
                    fr[2] = (_Float16)p0.z; fr[3] = (_Float16)p0.w;
                    fr[4] = (_Float16)p1.x; fr[5] = (_Float16)p1.y;
                    fr[6] = (_Float16)p1.z; fr[7] = (_Float16)p1.w;
                    a0[s][kk] = fr;
                }
            }
        }

        // ---- layer 0: H0^T = W0^T (LDS, A) x edges (B) ----
        f32x4 acc[2][8];
        #pragma unroll
        for (int s = 0; s < 2; ++s)
            #pragma unroll
            for (int j = 0; j < 8; ++j) acc[s][j] = (f32x4){0.f, 0.f, 0.f, 0.f};
        #pragma unroll
        for (int kk = 0; kk < 8; ++kk) {
            #pragma unroll
            for (int j = 0; j < 8; ++j) {
                half8 af = w0f[(kk * 8 + j) * 64 + l];
                acc[0][j] = __builtin_amdgcn_mfma_f32_16x16x32_f16(af, a0[0][kk], acc[0][j], 0, 0, 0);
                acc[1][j] = __builtin_amdgcn_mfma_f32_16x16x32_f16(af, a0[1][kk], acc[1][j], 0, 0, 0);
            }
        }

        // ---- L0 epilogue: bias+ELU+f16, register re-pack to B-frags ----
        half8 h0b[2][4];
        #pragma unroll
        for (int j = 0; j < 8; ++j) {
            half4v bb = *(const half4v*)&b0l[j * 16 + g * 4];
            const int kk2 = j >> 1, ib = (j & 1) * 4;
            #pragma unroll
            for (int s = 0; s < 2; ++s) {
                h0b[s][kk2][ib + 0] = (_Float16)elu(acc[s][j][0] + (float)bb[0]);
                h0b[s][kk2][ib + 1] = (_Float16)elu(acc[s][j][1] + (float)bb[1]);
                h0b[s][kk2][ib + 2] = (_Float16)elu(acc[s][j][2] + (float)bb[2]);
                h0b[s][kk2][ib + 3] = (_Float16)elu(acc[s][j][3] + (float)bb[3]);
            }
        }

        // ---- layer 1: W1^T frags streamed from global, prefetch depth 4 ----
        f32x4 acc1[2][8];
        #pragma unroll
        for (int s = 0; s < 2; ++s)
            #pragma unroll
            for (int j = 0; j < 8; ++j) acc1[s][j] = (f32x4){0.f, 0.f, 0.f, 0.f};
        half8 wbuf[4];
        #pragma unroll
        for (int p = 0; p < 4; ++p) wbuf[p] = w1f[p * 64 + l];
        #pragma unroll
        for (int fg = 0; fg < 32; ++fg) {
            half8 cur = wbuf[fg & 3];
            if (fg < 28) wbuf[fg & 3] = w1f[(fg + 4) * 64 + l];
            const int kk2 = fg >> 3, j2 = fg & 7;
            acc1[0][j2] = __builtin_amdgcn_mfma_f32_16x16x32_f16(cur, h0b[0][kk2], acc1[0][j2], 0, 0, 0);
            acc1[1][j2] = __builtin_amdgcn_mfma_f32_16x16x32_f16(cur, h0b[1][kk2], acc1[1][j2], 0, 0, 0);
        }

        // ---- L1 epilogue: bias+ELU+f16 re-pack ----
        half8 pb[2][4];
        #pragma unroll
        for (int j = 0; j < 8; ++j) {
            half4v bb = *(const half4v*)&b1l[j * 16 + g * 4];
            const int kk2 = j >> 1, ib = (j & 1) * 4;
            #pragma unroll
            for (int s = 0; s < 2; ++s) {
                pb[s][kk2][ib + 0] = (_Float16)elu(acc1[s][j][0] + (float)bb[0]);
                pb[s][kk2][ib + 1] = (_Float16)elu(acc1[s][j][1] + (float)bb[1]);
                pb[s][kk2][ib + 2] = (_Float16)elu(acc1[s][j][2] + (float)bb[2]);
                pb[s][kk2][ib + 3] = (_Float16)elu(acc1[s][j][3] + (float)bb[3]);
            }
        }

        // ---- final layer via MFMA with replicated-row W2: all D rows = p ----
        f32x4 acc2[2];
        acc2[0] = (f32x4){0.f, 0.f, 0.f, 0.f};
        acc2[1] = (f32x4){0.f, 0.f, 0.f, 0.f};
        #pragma unroll
        for (int kkf = 0; kkf < 4; ++kkf) {
            half8 wf = w2f[kkf * 64 + l];
            acc2[0] = __builtin_amdgcn_mfma_f32_16x16x32_f16(wf, pb[0][kkf], acc2[0], 0, 0, 0);
            acc2[1] = __builtin_amdgcn_mfma_f32_16x16x32_f16(wf, pb[1][kkf], acc2[1], 0, 0, 0);
        }

        // ---- sigmoid + store: quads 0/1 store sets 0/1 (32 lanes, 128 B) ----
        const float pv = (g & 1) ? acc2[1][0] : acc2[0][0];
        const float r = 1.f / (1.f + __expf(-(pv + b2s)));
        if (g < 2) op[e0 + g * 16 + n] = r;
    }
}

extern "C" void kernel_launch(void* const* d_in, const int* in_sizes, int n_in,
                              void* d_out, int out_size, void* d_ws, size_t ws_size,
                              hipStream_t stream) {
    const float* user_emb = (const float*)d_in[0];
    const float* item_emb = (const float*)d_in[1];
    const int* ui_src = (const int*)d_in[2];
    const int* ui_dst = (const int*)d_in[3];
    const int* iu_src = (const int*)d_in[4];
    const int* iu_dst = (const int*)d_in[5];
    const float* W0_ui = (const float*)d_in[6];
    const float* b0_ui = (const float*)d_in[7];
    const float* W1_ui = (const float*)d_in[8];
    const float* b1_ui = (const float*)d_in[9];
    const float* W2_ui = (const float*)d_in[10];
    const float* b2_ui = (const float*)d_in[11];
    const float* W0_iu = (const float*)d_in[12];
    const float* b0_iu = (const float*)d_in[13];
    const float* W1_iu = (const float*)d_in[14];
    const float* b1_iu = (const float*)d_in[15];
    const float* W2_iu = (const float*)d_in[16];
    const float* b2_iu = (const float*)d_in[17];
    float* out = (float*)d_out;

    const size_t need_full = (size_t)(WB + 2 * DSTRIDE) * sizeof(unsigned short);
    const size_t need_w    = (size_t)(2 * DSTRIDE) * sizeof(unsigned short);

    if (ws_size >= need_full) {
        _Float16* ws = (_Float16*)d_ws;
        prep_emb<<<dim3(18750), dim3(256), 0, stream>>>(user_emb, item_emb, ws);
        prep_w<<<dim3(51), dim3(256), 0, stream>>>(W0_ui, W1_ui, W2_ui, b0_ui, b1_ui,
                                                   W0_iu, W1_iu, W2_iu, b0_iu, b1_iu,
                                                   ws + WB);
        edge_mlp<true><<<dim3(1024), dim3(512), 0, stream>>>(
            ws, ws + WB, user_emb, item_emb,
            ui_src, ui_dst, iu_src, iu_dst, b2_ui, b2_iu, out);
    } else if (ws_size >= need_w) {
        _Float16* ws = (_Float16*)d_ws;
        prep_w<<<dim3(51), dim3(256), 0, stream>>>(W0_ui, W1_ui, W2_ui, b0_ui, b1_ui,
                                                   W0_iu, W1_iu, W2_iu, b0_iu, b1_iu,
                                                   ws);
        edge_mlp<false><<<dim3(1024), dim3(512), 0, stream>>>(
            ws, ws, user_emb, item_emb,
            ui_src, ui_dst, iu_src, iu_dst, b2_ui, b2_iu, out);
    }
}

// Round 3
// 1921.079 us; speedup vs baseline: 1.2290x; 1.2290x over previous
//
#include <hip/hip_runtime.h>
#include <cstdint>
#include <cstddef>

// ---------------------------------------------------------------------------
// EdgeDecoder, transposed formulation (register-budgeted for 4 waves/SIMD):
//   H0^T = W0^T · X^T   (W0^T A-frags from LDS, gathered edges = B operand)
//   H1^T = W1^T · H0^T  (W1^T A-frags streamed from prepacked global/L1-L2)
//   p    = (W2 replicated-rows) · H1^T
// Inter-layer C->B transform is a pure register re-pack (prepacked k-perm).
// Gathers are JIT-prefetched (depth 2) inside the L0 k-loop so the live set
// stays <=128 regs (64 AGPR acc + ~56 VGPR) -> no spills at launch_bounds(512,4).
// ---------------------------------------------------------------------------

#define E_EDGES   1000000
#define NTILES    31250          // E / 32
#define NUSER_H   12800000       // 100000*128 halfs
#define NITEM_H   6400000        // 50000*128
#define WB        19200000       // half index where prepacked weights start
#define DSTRIDE   51456          // per-decoder prepacked halfs
#define W1_OFF    32768          // within decoder region
#define B0_OFF    49152
#define B1_OFF    49280
#define W2_OFF    49408
// LDS (halfs): w0t 0..32767 | b0 | b1 | w2 frags   (70144 B -> 2 blocks/CU)
#define LDS_H     35072

typedef _Float16 half8  __attribute__((ext_vector_type(8)));
typedef _Float16 half4v __attribute__((ext_vector_type(4)));
typedef float    f32x4  __attribute__((ext_vector_type(4)));

__device__ __forceinline__ float elu(float x) {
    return x > 0.f ? x : (__expf(x) - 1.f);
}

// ---- prep: fp32 embeddings -> f16 tables ----------------------------------
__global__ void prep_emb(const float* __restrict__ user_emb,
                         const float* __restrict__ item_emb,
                         _Float16* __restrict__ ws) {
    int i = blockIdx.x * 256 + threadIdx.x;        // float4 index over 4.8M
    const float* src; _Float16* dst;
    if (i < 3200000) { src = user_emb; dst = ws; }
    else { i -= 3200000; src = item_emb; dst = ws + NUSER_H; }
    float4 f = ((const float4*)src)[i];
    half4v h;
    h[0] = (_Float16)f.x; h[1] = (_Float16)f.y;
    h[2] = (_Float16)f.z; h[3] = (_Float16)f.w;
    ((half4v*)dst)[i] = h;
}

// ---- prep: weights -> prepacked f16 fragment order ------------------------
__global__ void prep_w(const float* __restrict__ W0_ui, const float* __restrict__ W1_ui,
                       const float* __restrict__ W2_ui, const float* __restrict__ b0_ui,
                       const float* __restrict__ b1_ui,
                       const float* __restrict__ W0_iu, const float* __restrict__ W1_iu,
                       const float* __restrict__ W2_iu, const float* __restrict__ b0_iu,
                       const float* __restrict__ b1_iu,
                       _Float16* __restrict__ wdst) {
    const int wid = blockIdx.x * 4 + (threadIdx.x >> 6);
    const int l = threadIdx.x & 63;
    const int n = l & 15, g = l >> 4;
    if (wid < 128) {
        // W0^T A-frags: frag f=kk*8+j; lane: row c1 = j*16+n, k = kk*32+g*8+i
        const int dec = wid >> 6, f = wid & 63;
        const float* W0 = dec ? W0_iu : W0_ui;
        const int kk = f >> 3, j = f & 7;
        half8 fr;
        #pragma unroll
        for (int i = 0; i < 8; ++i)
            fr[i] = (_Float16)W0[(kk * 32 + g * 8 + i) * 128 + j * 16 + n];
        *(half8*)&wdst[dec * DSTRIDE + f * 512 + l * 8] = fr;
    } else if (wid < 192) {
        // W1^T A-frags with permuted k-order matching the register re-pack:
        // k-pos (kk2, quad g, i) <-> channel c1 = (2*kk2+(i>>2))*16 + g*4 + (i&3)
        const int q = wid - 128, dec = q >> 5, f = q & 31;
        const float* W1 = dec ? W1_iu : W1_ui;
        const int kk2 = f >> 3, j2 = f & 7;
        half8 fr;
        #pragma unroll
        for (int i = 0; i < 8; ++i) {
            const int c1 = (2 * kk2 + (i >> 2)) * 16 + g * 4 + (i & 3);
            fr[i] = (_Float16)W1[c1 * 128 + j2 * 16 + n];
        }
        *(half8*)&wdst[dec * DSTRIDE + W1_OFF + f * 512 + l * 8] = fr;
    } else if (wid < 200) {
        // W2 replicated-row A-frags, same permuted k-order over c2
        const int q = wid - 192, dec = q >> 2, kkf = q & 3;
        const float* W2 = dec ? W2_iu : W2_ui;
        half8 fr;
        #pragma unroll
        for (int i = 0; i < 8; ++i)
            fr[i] = (_Float16)W2[(2 * kkf + (i >> 2)) * 16 + g * 4 + (i & 3)];
        *(half8*)&wdst[dec * DSTRIDE + W2_OFF + kkf * 512 + l * 8] = fr;
    } else if (wid < 202) {
        const int dec = wid - 200;
        const float* b0 = dec ? b0_iu : b0_ui;
        const float* b1 = dec ? b1_iu : b1_ui;
        _Float16* d = wdst + dec * DSTRIDE;
        d[B0_OFF + 2 * l]     = (_Float16)b0[2 * l];
        d[B0_OFF + 2 * l + 1] = (_Float16)b0[2 * l + 1];
        d[B1_OFF + 2 * l]     = (_Float16)b1[2 * l];
        d[B1_OFF + 2 * l + 1] = (_Float16)b1[2 * l + 1];
    }
}

// ---- main ------------------------------------------------------------------
__global__ __launch_bounds__(512, 4) void edge_mlp(
    const _Float16* __restrict__ tab16,     // f16 tables base (user @0, item @NUSER_H)
    const _Float16* __restrict__ wpre,      // prepacked weights base
    const int* __restrict__ ui_src, const int* __restrict__ ui_dst,
    const int* __restrict__ iu_src, const int* __restrict__ iu_dst,
    const float* __restrict__ b2_ui, const float* __restrict__ b2_iu,
    float* __restrict__ out)
{
    __shared__ __align__(16) _Float16 lds[LDS_H];
    const int tid = threadIdx.x;
    const int l = tid & 63, w = tid >> 6;
    const int n = l & 15, g = l >> 4;
    const int dec = (int)(blockIdx.x >> 8);
    const int b8  = (int)(blockIdx.x & 255);

    const _Float16* stab = dec ? tab16 + NUSER_H : tab16;
    const _Float16* dtab = dec ? tab16 : tab16 + NUSER_H;
    const int* sidx = dec ? iu_src : ui_src;
    const int* didx = dec ? iu_dst : ui_dst;
    const _Float16* wreg = wpre + (size_t)dec * DSTRIDE;
    const float b2s = dec ? b2_iu[0] : b2_ui[0];
    float* op = out + dec * E_EDGES;

    // stage W0^T frags (64 KB) + biases + W2 frags into LDS
    #pragma unroll
    for (int q = 0; q < 8; ++q) {
        const int f = w * 8 + q;
        *(half8*)&lds[f * 512 + l * 8] = *(const half8*)&wreg[f * 512 + l * 8];
    }
    if (tid < 288)
        *(half8*)&lds[32768 + tid * 8] = *(const half8*)&wreg[B0_OFF + tid * 8];
    __syncthreads();

    const half8* w0f = (const half8*)lds;               // frag f: [f*64 + l]
    const _Float16* b0l = &lds[32768];
    const _Float16* b1l = &lds[32896];
    const half8* w2f = (const half8*)&lds[33024];       // frag kkf: [kkf*64 + l]
    const half8* w1f = (const half8*)&wreg[W1_OFF];     // global frags [f*64 + l]

    const f32x4 z4 = (f32x4){0.f, 0.f, 0.f, 0.f};

    int t = b8 * 8 + w;                  // 2048 waves per decoder
    int si0 = sidx[t * 32 + n];
    int si1 = sidx[t * 32 + 16 + n];
    int di0 = didx[t * 32 + n];
    int di1 = didx[t * 32 + 16 + n];

    while (true) {
        const int e0 = t * 32;
        // per-set row pointers (lane's quad selects the 8-half chunk)
        const _Float16* ps0 = stab + (((size_t)(unsigned)si0) << 7) + g * 8;
        const _Float16* ps1 = stab + (((size_t)(unsigned)si1) << 7) + g * 8;
        const _Float16* pd0 = dtab + (((size_t)(unsigned)di0) << 7) + g * 8;
        const _Float16* pd1 = dtab + (((size_t)(unsigned)di1) << 7) + g * 8;

        // rolling gather buffer, depth 2 (chunk c: src row c<4, dst row c>=4)
        half8 gb[2][2];
        gb[0][0] = *(const half8*)ps0;
        gb[0][1] = *(const half8*)ps1;
        gb[1][0] = *(const half8*)(ps0 + 32);
        gb[1][1] = *(const half8*)(ps1 + 32);

        // ---- layer 0: H0^T = W0^T (LDS, A) x edges (B) ----
        f32x4 acc[2][8];
        #pragma unroll
        for (int kk = 0; kk < 8; ++kk) {
            half8 cur0 = gb[kk & 1][0];
            half8 cur1 = gb[kk & 1][1];
            if (kk < 6) {
                const int c = kk + 2;
                const _Float16* q0 = (c < 4) ? ps0 + c * 32 : pd0 + (c - 4) * 32;
                const _Float16* q1 = (c < 4) ? ps1 + c * 32 : pd1 + (c - 4) * 32;
                gb[kk & 1][0] = *(const half8*)q0;
                gb[kk & 1][1] = *(const half8*)q1;
            }
            #pragma unroll
            for (int j = 0; j < 8; ++j) {
                half8 af = w0f[(kk * 8 + j) * 64 + l];
                if (kk == 0) {
                    acc[0][j] = __builtin_amdgcn_mfma_f32_16x16x32_f16(af, cur0, z4, 0, 0, 0);
                    acc[1][j] = __builtin_amdgcn_mfma_f32_16x16x32_f16(af, cur1, z4, 0, 0, 0);
                } else {
                    acc[0][j] = __builtin_amdgcn_mfma_f32_16x16x32_f16(af, cur0, acc[0][j], 0, 0, 0);
                    acc[1][j] = __builtin_amdgcn_mfma_f32_16x16x32_f16(af, cur1, acc[1][j], 0, 0, 0);
                }
            }
        }

        // prefetch next tile's indices (covered by L1/L2 compute)
        const int tn = t + 2048;
        const bool more = tn < NTILES;
        int nsi0 = 0, nsi1 = 0, ndi0 = 0, ndi1 = 0;
        if (more) {
            nsi0 = sidx[tn * 32 + n];
            nsi1 = sidx[tn * 32 + 16 + n];
            ndi0 = didx[tn * 32 + n];
            ndi1 = didx[tn * 32 + 16 + n];
        }

        // ---- L0 epilogue: bias+ELU+f16, register re-pack to B-frags ----
        half8 h0b[2][4];
        #pragma unroll
        for (int j = 0; j < 8; ++j) {
            half4v bb = *(const half4v*)&b0l[j * 16 + g * 4];
            const int kk2 = j >> 1, ib = (j & 1) * 4;
            #pragma unroll
            for (int s = 0; s < 2; ++s) {
                h0b[s][kk2][ib + 0] = (_Float16)elu(acc[s][j][0] + (float)bb[0]);
                h0b[s][kk2][ib + 1] = (_Float16)elu(acc[s][j][1] + (float)bb[1]);
                h0b[s][kk2][ib + 2] = (_Float16)elu(acc[s][j][2] + (float)bb[2]);
                h0b[s][kk2][ib + 3] = (_Float16)elu(acc[s][j][3] + (float)bb[3]);
            }
        }

        // ---- layer 1: W1^T frags streamed from global, prefetch depth 4 ----
        f32x4 acc1[2][8];
        half8 wbuf[4];
        #pragma unroll
        for (int p = 0; p < 4; ++p) wbuf[p] = w1f[p * 64 + l];
        #pragma unroll
        for (int fg = 0; fg < 32; ++fg) {
            half8 cur = wbuf[fg & 3];
            if (fg < 28) wbuf[fg & 3] = w1f[(fg + 4) * 64 + l];
            const int kk2 = fg >> 3, j2 = fg & 7;
            if (fg < 8) {
                acc1[0][j2] = __builtin_amdgcn_mfma_f32_16x16x32_f16(cur, h0b[0][kk2], z4, 0, 0, 0);
                acc1[1][j2] = __builtin_amdgcn_mfma_f32_16x16x32_f16(cur, h0b[1][kk2], z4, 0, 0, 0);
            } else {
                acc1[0][j2] = __builtin_amdgcn_mfma_f32_16x16x32_f16(cur, h0b[0][kk2], acc1[0][j2], 0, 0, 0);
                acc1[1][j2] = __builtin_amdgcn_mfma_f32_16x16x32_f16(cur, h0b[1][kk2], acc1[1][j2], 0, 0, 0);
            }
        }

        // ---- L1 epilogue: bias+ELU+f16 re-pack ----
        half8 pb[2][4];
        #pragma unroll
        for (int j = 0; j < 8; ++j) {
            half4v bb = *(const half4v*)&b1l[j * 16 + g * 4];
            const int kk2 = j >> 1, ib = (j & 1) * 4;
            #pragma unroll
            for (int s = 0; s < 2; ++s) {
                pb[s][kk2][ib + 0] = (_Float16)elu(acc1[s][j][0] + (float)bb[0]);
                pb[s][kk2][ib + 1] = (_Float16)elu(acc1[s][j][1] + (float)bb[1]);
                pb[s][kk2][ib + 2] = (_Float16)elu(acc1[s][j][2] + (float)bb[2]);
                pb[s][kk2][ib + 3] = (_Float16)elu(acc1[s][j][3] + (float)bb[3]);
            }
        }

        // ---- final layer via MFMA with replicated-row W2: all D rows = p ----
        f32x4 acc2[2];
        #pragma unroll
        for (int kkf = 0; kkf < 4; ++kkf) {
            half8 wf = w2f[kkf * 64 + l];
            if (kkf == 0) {
                acc2[0] = __builtin_amdgcn_mfma_f32_16x16x32_f16(wf, pb[0][kkf], z4, 0, 0, 0);
                acc2[1] = __builtin_amdgcn_mfma_f32_16x16x32_f16(wf, pb[1][kkf], z4, 0, 0, 0);
            } else {
                acc2[0] = __builtin_amdgcn_mfma_f32_16x16x32_f16(wf, pb[0][kkf], acc2[0], 0, 0, 0);
                acc2[1] = __builtin_amdgcn_mfma_f32_16x16x32_f16(wf, pb[1][kkf], acc2[1], 0, 0, 0);
            }
        }

        // ---- sigmoid + store: quads 0/1 store sets 0/1 (32 lanes, 128 B) ----
        const float pv = (g & 1) ? acc2[1][0] : acc2[0][0];
        const float r = 1.f / (1.f + __expf(-(pv + b2s)));
        if (g < 2) op[e0 + g * 16 + n] = r;

        if (!more) break;
        t = tn;
        si0 = nsi0; si1 = nsi1; di0 = ndi0; di1 = ndi1;
    }
}

extern "C" void kernel_launch(void* const* d_in, const int* in_sizes, int n_in,
                              void* d_out, int out_size, void* d_ws, size_t ws_size,
                              hipStream_t stream) {
    const float* user_emb = (const float*)d_in[0];
    const float* item_emb = (const float*)d_in[1];
    const int* ui_src = (const int*)d_in[2];
    const int* ui_dst = (const int*)d_in[3];
    const int* iu_src = (const int*)d_in[4];
    const int* iu_dst = (const int*)d_in[5];
    const float* W0_ui = (const float*)d_in[6];
    const float* b0_ui = (const float*)d_in[7];
    const float* W1_ui = (const float*)d_in[8];
    const float* b1_ui = (const float*)d_in[9];
    const float* W2_ui = (const float*)d_in[10];
    const float* b2_ui = (const float*)d_in[11];
    const float* W0_iu = (const float*)d_in[12];
    const float* b0_iu = (const float*)d_in[13];
    const float* W1_iu = (const float*)d_in[14];
    const float* b1_iu = (const float*)d_in[15];
    const float* W2_iu = (const float*)d_in[16];
    const float* b2_iu = (const float*)d_in[17];
    float* out = (float*)d_out;

    _Float16* ws = (_Float16*)d_ws;
    prep_emb<<<dim3(18750), dim3(256), 0, stream>>>(user_emb, item_emb, ws);
    prep_w<<<dim3(51), dim3(256), 0, stream>>>(W0_ui, W1_ui, W2_ui, b0_ui, b1_ui,
                                               W0_iu, W1_iu, W2_iu, b0_iu, b1_iu,
                                               ws + WB);
    edge_mlp<<<dim3(512), dim3(512), 0, stream>>>(
        ws, ws + WB, ui_src, ui_dst, iu_src, iu_dst, b2_ui, b2_iu, out);
}

// Round 5
// 1918.651 us; speedup vs baseline: 1.2306x; 1.0013x over previous
//
#include <hip/hip_runtime.h>
#include <cstdint>
#include <cstddef>

// ---------------------------------------------------------------------------
// EdgeDecoder, transposed formulation, j-OUTER schedule (anti-spill):
//   H0^T = W0^T · X^T   (W0^T A-frags from LDS, gathered edges = B operand)
//   H1^T = W1^T · H0^T  (W1^T A-frags streamed from prepacked global/L1-L2)
//   p    = (W2 replicated-rows) · H1^T
// j-outer keeps only 8 accumulator regs live (vs 64 with kk-outer), letting
// the unified VGPR/AGPR split float; edge frags a0[2][8] are MFMA operands
// and may be AGPR-allocated. Inter-layer C->B transform is a pure register
// re-pack (prepacked k-permutation on W1/W2). f32 biases in LDS; packed
// cvt_pkrtz epilogues (bit_cast shim for the __fp16 vs _Float16 vec types).
// ---------------------------------------------------------------------------

#define E_EDGES   1000000
#define NTILES    31250          // E / 32
#define NUSER_H   12800000       // 100000*128 halfs
#define WB        19200000       // half index where prepacked weights start
// per-decoder prepacked layout (halfs):
#define W1_OFF    32768          // W1 frags (16384)
#define W2_OFF    49152          // W2 frags (2048)
#define B0F_OFF   51200          // b0 as f32 (256 halfs = 128 floats)
#define B1F_OFF   51456          // b1 as f32
#define DSTRIDE   51712
// LDS (halfs): w0f 0..32767 | w2f 32768 | b0f 34816 | b1f 35072
#define LDS_H     35328          // 70656 B -> 2 blocks/CU

typedef _Float16 half8  __attribute__((ext_vector_type(8)));
typedef _Float16 half2v __attribute__((ext_vector_type(2)));
typedef _Float16 half4v __attribute__((ext_vector_type(4)));
typedef float    f32x4  __attribute__((ext_vector_type(4)));

union HB { half2v h2[4]; half8 h8; };

__device__ __forceinline__ float elu(float x) {
    return x > 0.f ? x : (__expf(x) - 1.f);
}

__device__ __forceinline__ half2v pk(float a, float b) {
    return __builtin_bit_cast(half2v, __builtin_amdgcn_cvt_pkrtz(a, b));
}

// ---- prep: fp32 embeddings -> f16 tables ----------------------------------
__global__ void prep_emb(const float* __restrict__ user_emb,
                         const float* __restrict__ item_emb,
                         _Float16* __restrict__ ws) {
    int i = blockIdx.x * 256 + threadIdx.x;        // float4 index over 4.8M
    const float* src; _Float16* dst;
    if (i < 3200000) { src = user_emb; dst = ws; }
    else { i -= 3200000; src = item_emb; dst = ws + NUSER_H; }
    float4 f = ((const float4*)src)[i];
    half4v h;
    h[0] = (_Float16)f.x; h[1] = (_Float16)f.y;
    h[2] = (_Float16)f.z; h[3] = (_Float16)f.w;
    ((half4v*)dst)[i] = h;
}

// ---- prep: weights -> prepacked f16 fragment order ------------------------
__global__ void prep_w(const float* __restrict__ W0_ui, const float* __restrict__ W1_ui,
                       const float* __restrict__ W2_ui, const float* __restrict__ b0_ui,
                       const float* __restrict__ b1_ui,
                       const float* __restrict__ W0_iu, const float* __restrict__ W1_iu,
                       const float* __restrict__ W2_iu, const float* __restrict__ b0_iu,
                       const float* __restrict__ b1_iu,
                       _Float16* __restrict__ wdst) {
    const int wid = blockIdx.x * 4 + (threadIdx.x >> 6);
    const int l = threadIdx.x & 63;
    const int n = l & 15, g = l >> 4;
    if (wid < 128) {
        // W0^T A-frags: frag f=kk*8+j; lane: row c1 = j*16+n, k = kk*32+g*8+i
        const int dec = wid >> 6, f = wid & 63;
        const float* W0 = dec ? W0_iu : W0_ui;
        const int kk = f >> 3, j = f & 7;
        half8 fr;
        #pragma unroll
        for (int i = 0; i < 8; ++i)
            fr[i] = (_Float16)W0[(kk * 32 + g * 8 + i) * 128 + j * 16 + n];
        *(half8*)&wdst[dec * DSTRIDE + f * 512 + l * 8] = fr;
    } else if (wid < 192) {
        // W1^T A-frags with permuted k-order matching the register re-pack:
        // k-pos (kk2, quad g, i) <-> channel c1 = (2*kk2+(i>>2))*16 + g*4 + (i&3)
        const int q = wid - 128, dec = q >> 5, f = q & 31;
        const float* W1 = dec ? W1_iu : W1_ui;
        const int kk2 = f >> 3, j2 = f & 7;
        half8 fr;
        #pragma unroll
        for (int i = 0; i < 8; ++i) {
            const int c1 = (2 * kk2 + (i >> 2)) * 16 + g * 4 + (i & 3);
            fr[i] = (_Float16)W1[c1 * 128 + j2 * 16 + n];
        }
        *(half8*)&wdst[dec * DSTRIDE + W1_OFF + f * 512 + l * 8] = fr;
    } else if (wid < 200) {
        // W2 replicated-row A-frags, same permuted k-order over c2
        const int q = wid - 192, dec = q >> 2, kkf = q & 3;
        const float* W2 = dec ? W2_iu : W2_ui;
        half8 fr;
        #pragma unroll
        for (int i = 0; i < 8; ++i)
            fr[i] = (_Float16)W2[(2 * kkf + (i >> 2)) * 16 + g * 4 + (i & 3)];
        *(half8*)&wdst[dec * DSTRIDE + W2_OFF + kkf * 512 + l * 8] = fr;
    } else if (wid < 202) {
        // biases as f32
        const int dec = wid - 200;
        const float* b0 = dec ? b0_iu : b0_ui;
        const float* b1 = dec ? b1_iu : b1_ui;
        float* d0 = (float*)&wdst[dec * DSTRIDE + B0F_OFF];
        float* d1 = (float*)&wdst[dec * DSTRIDE + B1F_OFF];
        d0[2 * l]     = b0[2 * l];
        d0[2 * l + 1] = b0[2 * l + 1];
        d1[2 * l]     = b1[2 * l];
        d1[2 * l + 1] = b1[2 * l + 1];
    }
}

// ---- main ------------------------------------------------------------------
__global__ __launch_bounds__(512, 4) void edge_mlp(
    const _Float16* __restrict__ tab16,     // f16 tables base (user @0, item @NUSER_H)
    const _Float16* __restrict__ wpre,      // prepacked weights base
    const int* __restrict__ ui_src, const int* __restrict__ ui_dst,
    const int* __restrict__ iu_src, const int* __restrict__ iu_dst,
    const float* __restrict__ b2_ui, const float* __restrict__ b2_iu,
    float* __restrict__ out)
{
    __shared__ __align__(16) _Float16 lds[LDS_H];
    const int tid = threadIdx.x;
    const int l = tid & 63, w = tid >> 6;
    const int n = l & 15, g = l >> 4;
    const int dec = (int)(blockIdx.x >> 8);
    const int b8  = (int)(blockIdx.x & 255);

    const _Float16* stab = dec ? tab16 + NUSER_H : tab16;
    const _Float16* dtab = dec ? tab16 : tab16 + NUSER_H;
    const int* sidx = dec ? iu_src : ui_src;
    const int* didx = dec ? iu_dst : ui_dst;
    const _Float16* wreg = wpre + (size_t)dec * DSTRIDE;
    const float b2s = dec ? b2_iu[0] : b2_ui[0];
    float* op = out + dec * E_EDGES;

    // stage W0^T frags (64 KB) + W2 frags + f32 biases into LDS
    #pragma unroll
    for (int q = 0; q < 8; ++q) {
        const int f = w * 8 + q;
        *(half8*)&lds[f * 512 + l * 8] = *(const half8*)&wreg[f * 512 + l * 8];
    }
    if (tid < 320)
        *(half8*)&lds[32768 + tid * 8] = *(const half8*)&wreg[W2_OFF + tid * 8];
    __syncthreads();

    const half8* w0f = (const half8*)lds;               // frag f=kk*8+j: [f*64+l]
    const half8* w2f = (const half8*)&lds[32768];       // frag kkf: [kkf*64+l]
    const float* b0f = (const float*)&lds[34816];
    const float* b1f = (const float*)&lds[35072];
    const half8* w1f = (const half8*)&wreg[W1_OFF];     // frag f=kk2*8+j2: [f*64+l]

    const f32x4 z4 = (f32x4){0.f, 0.f, 0.f, 0.f};

    int t = b8 * 8 + w;                  // 2048 waves per decoder
    int si0 = sidx[t * 32 + n];
    int si1 = sidx[t * 32 + 16 + n];
    int di0 = didx[t * 32 + n];
    int di1 = didx[t * 32 + 16 + n];

    while (true) {
        const int e0 = t * 32;
        const _Float16* ps0 = stab + (((size_t)(unsigned)si0) << 7) + g * 8;
        const _Float16* ps1 = stab + (((size_t)(unsigned)si1) << 7) + g * 8;
        const _Float16* pd0 = dtab + (((size_t)(unsigned)di0) << 7) + g * 8;
        const _Float16* pd1 = dtab + (((size_t)(unsigned)di1) << 7) + g * 8;

        // ---- gather all 16 chunks, in consumption order (compiler pipelines
        //      via fine-grained vmcnt against the j=0 MFMA chain) ----
        half8 a0[2][8];
        #pragma unroll
        for (int kk = 0; kk < 4; ++kk) {
            a0[0][kk] = *(const half8*)(ps0 + kk * 32);
            a0[1][kk] = *(const half8*)(ps1 + kk * 32);
        }
        #pragma unroll
        for (int kk = 0; kk < 4; ++kk) {
            a0[0][4 + kk] = *(const half8*)(pd0 + kk * 32);
            a0[1][4 + kk] = *(const half8*)(pd1 + kk * 32);
        }

        // ---- layer 0, j-outer: 8 acc regs live, epilogue per j ----
        HB hb[2][4];
        #pragma unroll
        for (int j = 0; j < 8; ++j) {
            half8 af = w0f[j * 64 + l];
            f32x4 c0 = __builtin_amdgcn_mfma_f32_16x16x32_f16(af, a0[0][0], z4, 0, 0, 0);
            f32x4 c1 = __builtin_amdgcn_mfma_f32_16x16x32_f16(af, a0[1][0], z4, 0, 0, 0);
            #pragma unroll
            for (int kk = 1; kk < 8; ++kk) {
                half8 ak = w0f[(kk * 8 + j) * 64 + l];
                c0 = __builtin_amdgcn_mfma_f32_16x16x32_f16(ak, a0[0][kk], c0, 0, 0, 0);
                c1 = __builtin_amdgcn_mfma_f32_16x16x32_f16(ak, a0[1][kk], c1, 0, 0, 0);
            }
            f32x4 bb = *(const f32x4*)&b0f[j * 16 + g * 4];
            const int kk2 = j >> 1, p = (j & 1) * 2;
            hb[0][kk2].h2[p]     = pk(elu(c0[0] + bb[0]), elu(c0[1] + bb[1]));
            hb[0][kk2].h2[p + 1] = pk(elu(c0[2] + bb[2]), elu(c0[3] + bb[3]));
            hb[1][kk2].h2[p]     = pk(elu(c1[0] + bb[0]), elu(c1[1] + bb[1]));
            hb[1][kk2].h2[p + 1] = pk(elu(c1[2] + bb[2]), elu(c1[3] + bb[3]));
        }

        // ---- next-tile index prefetch (a0 dead now) ----
        const int tn = t + 2048;
        const bool more = tn < NTILES;
        int nsi0 = 0, nsi1 = 0, ndi0 = 0, ndi1 = 0;
        if (more) {
            nsi0 = sidx[tn * 32 + n];
            nsi1 = sidx[tn * 32 + 16 + n];
            ndi0 = didx[tn * 32 + n];
            ndi1 = didx[tn * 32 + 16 + n];
        }

        // ---- layer 1, j2-outer: 4 W1 frags in flight, 8 acc regs ----
        HB pb[2][4];
        #pragma unroll
        for (int j2 = 0; j2 < 8; ++j2) {
            half8 wa0 = w1f[j2 * 64 + l];
            half8 wa1 = w1f[(8 + j2) * 64 + l];
            half8 wa2 = w1f[(16 + j2) * 64 + l];
            half8 wa3 = w1f[(24 + j2) * 64 + l];
            f32x4 c0 = __builtin_amdgcn_mfma_f32_16x16x32_f16(wa0, hb[0][0].h8, z4, 0, 0, 0);
            f32x4 c1 = __builtin_amdgcn_mfma_f32_16x16x32_f16(wa0, hb[1][0].h8, z4, 0, 0, 0);
            c0 = __builtin_amdgcn_mfma_f32_16x16x32_f16(wa1, hb[0][1].h8, c0, 0, 0, 0);
            c1 = __builtin_amdgcn_mfma_f32_16x16x32_f16(wa1, hb[1][1].h8, c1, 0, 0, 0);
            c0 = __builtin_amdgcn_mfma_f32_16x16x32_f16(wa2, hb[0][2].h8, c0, 0, 0, 0);
            c1 = __builtin_amdgcn_mfma_f32_16x16x32_f16(wa2, hb[1][2].h8, c1, 0, 0, 0);
            c0 = __builtin_amdgcn_mfma_f32_16x16x32_f16(wa3, hb[0][3].h8, c0, 0, 0, 0);
            c1 = __builtin_amdgcn_mfma_f32_16x16x32_f16(wa3, hb[1][3].h8, c1, 0, 0, 0);
            f32x4 bb = *(const f32x4*)&b1f[j2 * 16 + g * 4];
            const int kk2 = j2 >> 1, p = (j2 & 1) * 2;
            pb[0][kk2].h2[p]     = pk(elu(c0[0] + bb[0]), elu(c0[1] + bb[1]));
            pb[0][kk2].h2[p + 1] = pk(elu(c0[2] + bb[2]), elu(c0[3] + bb[3]));
            pb[1][kk2].h2[p]     = pk(elu(c1[0] + bb[0]), elu(c1[1] + bb[1]));
            pb[1][kk2].h2[p + 1] = pk(elu(c1[2] + bb[2]), elu(c1[3] + bb[3]));
        }

        // ---- final layer via MFMA with replicated-row W2: all D rows = p ----
        f32x4 d0 = __builtin_amdgcn_mfma_f32_16x16x32_f16(w2f[l], pb[0][0].h8, z4, 0, 0, 0);
        f32x4 d1 = __builtin_amdgcn_mfma_f32_16x16x32_f16(w2f[l], pb[1][0].h8, z4, 0, 0, 0);
        #pragma unroll
        for (int kkf = 1; kkf < 4; ++kkf) {
            half8 wf = w2f[kkf * 64 + l];
            d0 = __builtin_amdgcn_mfma_f32_16x16x32_f16(wf, pb[0][kkf].h8, d0, 0, 0, 0);
            d1 = __builtin_amdgcn_mfma_f32_16x16x32_f16(wf, pb[1][kkf].h8, d1, 0, 0, 0);
        }

        // ---- sigmoid + store: quads 0/1 store sets 0/1 (32 lanes, 128 B) ----
        const float pv = (g & 1) ? d1[0] : d0[0];
        const float r = 1.f / (1.f + __expf(-(pv + b2s)));
        if (g < 2) op[e0 + g * 16 + n] = r;

        if (!more) break;
        t = tn;
        si0 = nsi0; si1 = nsi1; di0 = ndi0; di1 = ndi1;
    }
}

extern "C" void kernel_launch(void* const* d_in, const int* in_sizes, int n_in,
                              void* d_out, int out_size, void* d_ws, size_t ws_size,
                              hipStream_t stream) {
    const float* user_emb = (const float*)d_in[0];
    const float* item_emb = (const float*)d_in[1];
    const int* ui_src = (const int*)d_in[2];
    const int* ui_dst = (const int*)d_in[3];
    const int* iu_src = (const int*)d_in[4];
    const int* iu_dst = (const int*)d_in[5];
    const float* W0_ui = (const float*)d_in[6];
    const float* b0_ui = (const float*)d_in[7];
    const float* W1_ui = (const float*)d_in[8];
    const float* b1_ui = (const float*)d_in[9];
    const float* W2_ui = (const float*)d_in[10];
    const float* b2_ui = (const float*)d_in[11];
    const float* W0_iu = (const float*)d_in[12];
    const float* b0_iu = (const float*)d_in[13];
    const float* W1_iu = (const float*)d_in[14];
    const float* b1_iu = (const float*)d_in[15];
    const float* W2_iu = (const float*)d_in[16];
    const float* b2_iu = (const float*)d_in[17];
    float* out = (float*)d_out;

    _Float16* ws = (_Float16*)d_ws;
    prep_emb<<<dim3(18750), dim3(256), 0, stream>>>(user_emb, item_emb, ws);
    prep_w<<<dim3(51), dim3(256), 0, stream>>>(W0_ui, W1_ui, W2_ui, b0_ui, b1_ui,
                                               W0_iu, W1_iu, W2_iu, b0_iu, b1_iu,
                                               ws + WB);
    edge_mlp<<<dim3(512), dim3(512), 0, stream>>>(
        ws, ws + WB, ui_src, ui_dst, iu_src, iu_dst, b2_ui, b2_iu, out);
}